// Round 6
// baseline (196.717 us; speedup 1.0000x reference)
//
#include <hip/hip_runtime.h>
#include <hip/hip_bf16.h>

#define BN 8
#define LN 4096
#define HN 2048
#define EN 512
#define KN 64
#define LT 64
#define NIT 64

typedef __attribute__((ext_vector_type(8))) short bf16x8;
typedef __attribute__((ext_vector_type(4))) float f32x4;
typedef __attribute__((ext_vector_type(4))) unsigned u32x4;

__device__ __forceinline__ short f2b(float x) {
  union { float f; unsigned u; } v; v.f = x;
  unsigned r = v.u + 0x7fffu + ((v.u >> 16) & 1u);  // RNE f32->bf16
  return (short)(r >> 16);
}

__device__ __forceinline__ bf16x8 cvt8(const float* __restrict__ p) {
  f32x4 a = *(const f32x4*)(p);
  f32x4 b = *(const f32x4*)(p + 4);
  bf16x8 r;
  r[0] = f2b(a[0]); r[1] = f2b(a[1]); r[2] = f2b(a[2]); r[3] = f2b(a[3]);
  r[4] = f2b(b[0]); r[5] = f2b(b[1]); r[6] = f2b(b[2]); r[7] = f2b(b[3]);
  return r;
}

__device__ __forceinline__ void gload16(const void* g, void* s) {
  __builtin_amdgcn_global_load_lds(
      (const __attribute__((address_space(1))) unsigned int*)(unsigned long long)g,
      (__attribute__((address_space(3))) unsigned int*)(unsigned int)(unsigned long long)s,
      16, 0, 0);
}

// ---------- prep: x (scaled) and y f32 -> bf16, one launch ----------
__global__ __launch_bounds__(256) void prep_cvt2(const float* __restrict__ xs,
                                                 short* __restrict__ xo,
                                                 const float* __restrict__ ys,
                                                 short* __restrict__ yo) {
  int bx = blockIdx.x;
  const float* src;
  short* dst;
  float scale;
  int i;
  if (bx < 1024) {
    i = bx * 256 + threadIdx.x;
    src = xs; dst = xo; scale = 0.125f * 1.4426950408889634f;
  } else {
    i = (bx - 1024) * 256 + threadIdx.x;
    src = ys; dst = yo; scale = 1.0f;
  }
  f32x4 a = *(const f32x4*)(src + (size_t)i * 8);
  f32x4 b = *(const f32x4*)(src + (size_t)i * 8 + 4);
  bf16x8 r;
  r[0] = f2b(a[0] * scale); r[1] = f2b(a[1] * scale);
  r[2] = f2b(a[2] * scale); r[3] = f2b(a[3] * scale);
  r[4] = f2b(b[0] * scale); r[5] = f2b(b[1] * scale);
  r[6] = f2b(b[2] * scale); r[7] = f2b(b[3] * scale);
  *(bf16x8*)(dst + (size_t)i * 8) = r;
}

// ---------- merged: prep_v (blocks 0..4095) || stats (blocks 4096..5119) ----------
__global__ __launch_bounds__(256) void k_pv_stats(const float* __restrict__ vals,
                                                  short* __restrict__ valsT,
                                                  const short* __restrict__ xb,
                                                  const short* __restrict__ yb,
                                                  float* __restrict__ ps) {
  __shared__ unsigned trT[2048];
  const int bx = blockIdx.x;
  const int tid = threadIdx.x;
  if (bx < 4096) {
    const int b = bx >> 9;
    const int e0 = ((bx >> 6) & 7) * 64;
    const int l0 = (bx & 63) * 64;
    {
      int lr2 = tid >> 3;
      int ec = (tid & 7) * 8;
      const float* r0 = vals + ((size_t)b * LN + l0 + 2 * lr2) * EN + e0 + ec;
      const float* r1 = r0 + EN;
      f32x4 a0 = *(const f32x4*)r0, a1 = *(const f32x4*)(r0 + 4);
      f32x4 c0 = *(const f32x4*)r1, c1 = *(const f32x4*)(r1 + 4);
#pragma unroll
      for (int j = 0; j < 8; ++j) {
        float lo = (j < 4) ? a0[j] : a1[j - 4];
        float hi = (j < 4) ? c0[j] : c1[j - 4];
        unsigned dw = (unsigned)(unsigned short)f2b(lo) |
                      ((unsigned)(unsigned short)f2b(hi) << 16);
        int e = ec + j;
        int sz = (((e >> 3) ^ e) & 7) << 2;
        trT[e * 32 + (lr2 ^ sz)] = dw;
      }
    }
    __syncthreads();
    {
      int er = tid >> 2, lq = (tid & 3) * 8;
      int sr = ((er >> 3) ^ er) & 7;
      const unsigned* base = trT + er * 32;
      u32x4 u0 = *(const u32x4*)(base + ((((lq >> 2) + 0) ^ sr) << 2));
      u32x4 u1 = *(const u32x4*)(base + ((((lq >> 2) + 1) ^ sr) << 2));
      short* dst = valsT + ((size_t)b * EN + e0 + er) * LN + l0 + 2 * lq;
      *(u32x4*)dst = u0;
      *(u32x4*)(dst + 8) = u1;
    }
  } else {
    const int idx = bx - 4096;
    const int b = (idx >> 5) & 7, hc = idx >> 8;
    const int w = tid >> 6, lane = tid & 63;
    const int row = lane & 15, g = lane >> 4;
    const int lb = (idx & 31) * 128 + w * 32;
    const size_t bL = (size_t)b * LN, bH = (size_t)b * HN;
    bf16x8 xa[2][2];
#pragma unroll
    for (int lt = 0; lt < 2; ++lt) {
      const short* xp = xb + ((bL + lb + lt * 16 + row) << 6) + 8 * g;
      xa[lt][0] = *(const bf16x8*)xp;
      xa[lt][1] = *(const bf16x8*)(xp + 32);
    }
    float s[2][4] = {{0.f, 0.f, 0.f, 0.f}, {0.f, 0.f, 0.f, 0.f}};
    const short* ybase = yb + ((bH + hc * 512 + row) << 6) + 8 * g;
#pragma unroll 2
    for (int it = 0; it < 32; ++it) {
      const short* yp = ybase + ((size_t)it << 10);
      bf16x8 y0 = *(const bf16x8*)yp;
      bf16x8 y1 = *(const bf16x8*)(yp + 32);
#pragma unroll
      for (int lt = 0; lt < 2; ++lt) {
        f32x4 a = {0.f, 0.f, 0.f, 0.f};
        a = __builtin_amdgcn_mfma_f32_16x16x32_bf16(xa[lt][0], y0, a, 0, 0, 0);
        a = __builtin_amdgcn_mfma_f32_16x16x32_bf16(xa[lt][1], y1, a, 0, 0, 0);
#pragma unroll
        for (int r = 0; r < 4; ++r) s[lt][r] += __builtin_amdgcn_exp2f(a[r]);
      }
    }
#pragma unroll
    for (int d = 1; d < 16; d <<= 1)
#pragma unroll
      for (int lt = 0; lt < 2; ++lt)
#pragma unroll
        for (int r = 0; r < 4; ++r) s[lt][r] += __shfl_xor(s[lt][r], d);
    if (row == 0) {
#pragma unroll
      for (int lt = 0; lt < 2; ++lt)
#pragma unroll
        for (int r = 0; r < 4; ++r)
          ps[(size_t)hc * (BN * LN) + bL + lb + lt * 16 + 4 * g + r] = s[lt][r];
    }
  }
}

__global__ void k_comb(const float* __restrict__ ps, float* __restrict__ wv) {
  int idx = blockIdx.x * 256 + threadIdx.x;
  float z = ps[idx] + ps[BN * LN + idx] + ps[2 * BN * LN + idx] + ps[3 * BN * LN + idx];
  wv[idx] = 1.0f / z;
}

// ---------- main v5: wave 64x64 tiles, LT=64, 2 produce waves, 1 barrier/iter ----------
// LDS: vT[2]x32768 @0 | xT[3]x8192 @65536 | pT[2]x16384 @90112 | sw[3]x256 @122880
__global__ __launch_bounds__(512, 2) void k_main5(
    const short* __restrict__ valsT, const short* __restrict__ xb,
    const short* __restrict__ yb, const float* __restrict__ wv,
    float* __restrict__ out) {
  __shared__ __align__(16) char smem[123648];
  const int tid = threadIdx.x;
  const int w = tid >> 6, lane = tid & 63;
  const int row = lane & 15, g = lane >> 4;

  const int f = blockIdx.x;
  const int b = f & 7;                  // XCD f%8 <- batch b (valsT[b] 4MB per XCD L2)
  const int rest = f >> 3;              // 0..31
  const int hb = (rest & 15) * 128;
  const int eb = (rest >> 4) * 256;
  const size_t bL = (size_t)b * LN, bH = (size_t)b * HN;

  const int wbase = __builtin_amdgcn_readfirstlane(tid & ~63);

  // ---- staging source pointers ----
  const short* vsrc[4];
#pragma unroll
  for (int j = 0; j < 4; ++j) {
    int i = j * 512 + tid;
    int e = i >> 3, ch = i & 7, sl = ch ^ (e & 7);
    vsrc[j] = valsT + (((size_t)b * EN + eb + e) << 12) + 8 * sl;
  }
  const short* xsrc = xb + ((bL + (tid >> 3)) << 6) + 8 * ((tid & 7) ^ ((tid >> 3) & 7));
  const float* ssrc = wv + bL + (lane << 2);  // lanes 0..15 of wave 0

  auto stage_xs = [&](int t) {
    int m3 = t % 3;
    gload16(xsrc + ((size_t)t << 12), smem + 65536 + m3 * 8192 + wbase * 16);
    if (tid < 16)
      gload16(ssrc + t * 64, smem + 122880 + m3 * 256);
  };
  auto stage_v = [&](int t) {
    char* vb_ = smem + (t & 1) * 32768 + wbase * 16;
#pragma unroll
    for (int j = 0; j < 4; ++j)
      gload16(vsrc[j] + t * 64, vb_ + j * 8192);
  };

  // ---- produce role (waves 0,1): y A..B-frags for 4 h-tiles each ----
  bf16x8 ya[4][2];
  if (w < 2) {
#pragma unroll
    for (int j = 0; j < 4; ++j) {
      const short* yp = yb + ((bH + hb + (w * 4 + j) * 16 + row) << 6) + 8 * g;
      ya[j][0] = *(const bf16x8*)yp;
      ya[j][1] = *(const bf16x8*)(yp + 32);
    }
  }

  f32x4 acc[4][4];
#pragma unroll
  for (int at = 0; at < 4; ++at)
#pragma unroll
    for (int n = 0; n < 4; ++n) acc[at][n] = (f32x4){0.f, 0.f, 0.f, 0.f};

  // produce P(t) -> pT[t&1]: S^T tiles 128h x 64l via 16x16x32, exp2, pack
  auto produce = [&](int t) {
    if (w >= 2) return;
    const char* xbuf = smem + 65536 + (t % 3) * 8192;
    const float* swp = (const float*)(smem + 122880 + (t % 3) * 256);
    char* pdst = smem + 90112 + (t & 1) * 16384;
#pragma unroll
    for (int lt = 0; lt < 4; ++lt) {
      int lr = lt * 16 + row;
      bf16x8 xa0 = *(const bf16x8*)(xbuf + lr * 128 + ((g ^ (lr & 7)) << 4));
      bf16x8 xa1 = *(const bf16x8*)(xbuf + lr * 128 + (((4 + g) ^ (lr & 7)) << 4));
      f32x4 sws = *(const f32x4*)(swp + lt * 16 + 4 * g);
#pragma unroll
      for (int j = 0; j < 4; ++j) {
        f32x4 s4 = {0.f, 0.f, 0.f, 0.f};
        s4 = __builtin_amdgcn_mfma_f32_16x16x32_bf16(xa0, ya[j][0], s4, 0, 0, 0);
        s4 = __builtin_amdgcn_mfma_f32_16x16x32_bf16(xa1, ya[j][1], s4, 0, 0, 0);
        int hq = (w * 4 + j) * 16 + row;
        int phys = (lt * 2 + (g >> 1)) ^ (hq & 7);
        unsigned u0 = (unsigned)(unsigned short)f2b(__builtin_amdgcn_exp2f(s4[0]) * sws[0]) |
                      ((unsigned)(unsigned short)f2b(__builtin_amdgcn_exp2f(s4[1]) * sws[1]) << 16);
        unsigned u1 = (unsigned)(unsigned short)f2b(__builtin_amdgcn_exp2f(s4[2]) * sws[2]) |
                      ((unsigned)(unsigned short)f2b(__builtin_amdgcn_exp2f(s4[3]) * sws[3]) << 16);
        *(unsigned long long*)(pdst + hq * 128 + phys * 16 + (g & 1) * 8) =
            (unsigned long long)u0 | ((unsigned long long)u1 << 32);
      }
    }
  };

  // consume tile t: acc += P^T x V
  auto consume = [&](int t) {
    const char* vbuf = smem + (t & 1) * 32768;
    const char* pbuf = smem + 90112 + (t & 1) * 16384;
    bf16x8 pa[4][2];
#pragma unroll
    for (int at = 0; at < 4; ++at) {
      int hq = (w >> 2) * 64 + at * 16 + row;
#pragma unroll
      for (int ks = 0; ks < 2; ++ks)
        pa[at][ks] = *(const bf16x8*)(pbuf + hq * 128 + (((ks * 4 + g) ^ (hq & 7)) << 4));
    }
    __builtin_amdgcn_s_setprio(1);
#pragma unroll
    for (int n = 0; n < 4; ++n) {
      int el = (w & 3) * 64 + n * 16 + row;
      bf16x8 vb0 = *(const bf16x8*)(vbuf + el * 128 + ((g ^ (el & 7)) << 4));
      bf16x8 vb1 = *(const bf16x8*)(vbuf + el * 128 + (((4 + g) ^ (el & 7)) << 4));
#pragma unroll
      for (int at = 0; at < 4; ++at) {
        acc[at][n] = __builtin_amdgcn_mfma_f32_16x16x32_bf16(pa[at][0], vb0, acc[at][n], 0, 0, 0);
        acc[at][n] = __builtin_amdgcn_mfma_f32_16x16x32_bf16(pa[at][1], vb1, acc[at][n], 0, 0, 0);
      }
    }
    __builtin_amdgcn_s_setprio(0);
  };

  // ---- prologue ----
  stage_xs(0);
  stage_xs(1);
  stage_v(0);
  asm volatile("s_waitcnt vmcnt(0)" ::: "memory");
  __builtin_amdgcn_s_barrier();
  asm volatile("" ::: "memory");
  produce(0);
  asm volatile("s_waitcnt lgkmcnt(0)" ::: "memory");
  __builtin_amdgcn_s_barrier();
  asm volatile("" ::: "memory");

  for (int it = 0; it < NIT; ++it) {
    if (it + 2 < NIT) stage_xs(it + 2);
    if (it + 1 < NIT) {
      stage_v(it + 1);
      produce(it + 1);
    }
    consume(it);
    if (it + 1 < NIT) {
      asm volatile("s_waitcnt vmcnt(0) lgkmcnt(0)" ::: "memory");
      __builtin_amdgcn_s_barrier();
      asm volatile("" ::: "memory");
    }
  }

#pragma unroll
  for (int at = 0; at < 4; ++at)
#pragma unroll
    for (int n = 0; n < 4; ++n)
#pragma unroll
      for (int r = 0; r < 4; ++r) {
        int h = hb + (w >> 2) * 64 + at * 16 + 4 * g + r;
        int e = eb + (w & 3) * 64 + n * 16 + row;
        out[(bH + h) * (size_t)EN + e] = acc[at][n][r];
      }
}

// ================= fallback path (round-1 kernels, ws < 40.5 MB) =================
__global__ __launch_bounds__(256) void k_stats_o(const float* __restrict__ xd,
                                                 const float* __restrict__ yd,
                                                 float* __restrict__ mz) {
  const int b = blockIdx.y;
  const int w = threadIdx.x >> 6;
  const int lane = threadIdx.x & 63;
  const int row = lane & 15, g = lane >> 4;
  const int lb = blockIdx.x * 64 + w * 16;
  const float* xp = xd + ((size_t)b * LN + lb + row) * KN + g * 8;
  bf16x8 a0 = cvt8(xp), a1 = cvt8(xp + 32);
  float m[4], s[4];
#pragma unroll
  for (int r = 0; r < 4; ++r) { m[r] = -1e30f; s[r] = 0.f; }
  const float* ybp = yd + ((size_t)b * HN + row) * KN + g * 8;
  for (int h0 = 0; h0 < HN; h0 += 16) {
    bf16x8 b0 = cvt8(ybp + (size_t)h0 * KN);
    bf16x8 b1 = cvt8(ybp + (size_t)h0 * KN + 32);
    f32x4 acc = {0.f, 0.f, 0.f, 0.f};
    acc = __builtin_amdgcn_mfma_f32_16x16x32_bf16(a0, b0, acc, 0, 0, 0);
    acc = __builtin_amdgcn_mfma_f32_16x16x32_bf16(a1, b1, acc, 0, 0, 0);
#pragma unroll
    for (int r = 0; r < 4; ++r) {
      float v = acc[r] * 0.125f;
      float mn = fmaxf(m[r], v);
      s[r] = s[r] * __expf(m[r] - mn) + __expf(v - mn);
      m[r] = mn;
    }
  }
#pragma unroll
  for (int d = 1; d < 16; d <<= 1) {
#pragma unroll
    for (int r = 0; r < 4; ++r) {
      float mo = __shfl_xor(m[r], d);
      float so = __shfl_xor(s[r], d);
      float mn = fmaxf(m[r], mo);
      s[r] = s[r] * __expf(m[r] - mn) + so * __expf(mo - mn);
      m[r] = mn;
    }
  }
  if (row == 0) {
#pragma unroll
    for (int r = 0; r < 4; ++r) {
      size_t idx = (size_t)b * LN + lb + 4 * g + r;
      mz[idx] = m[r];
      mz[(size_t)BN * LN + idx] = 1.0f / s[r];
    }
  }
}

__global__ __launch_bounds__(512) void k_main_o(const float* __restrict__ vals,
                                                const float* __restrict__ xd,
                                                const float* __restrict__ yd,
                                                const float* __restrict__ mz,
                                                float* __restrict__ out) {
  __shared__ short vT[256][34];
  __shared__ short pT[128][34];
  __shared__ short xT[32][72];
  __shared__ float smm[32], smz[32];
  const int b = blockIdx.z;
  const int hb = blockIdx.x * 128;
  const int eb = blockIdx.y * 256;
  const int tid = threadIdx.x;
  const int w = tid >> 6, lane = tid & 63;
  const int row = lane & 15, g = lane >> 4;
  const float* yp = yd + ((size_t)b * HN + hb + w * 16 + row) * KN + g * 8;
  bf16x8 ya0 = cvt8(yp), ya1 = cvt8(yp + 32);
  f32x4 acc[16];
#pragma unroll
  for (int n = 0; n < 16; ++n) acc[n] = (f32x4){0.f, 0.f, 0.f, 0.f};
  const float* mzb = mz + (size_t)b * LN;
  const float* rzb = mz + (size_t)BN * LN + (size_t)b * LN;
  for (int l0 = 0; l0 < LN; l0 += 32) {
    __syncthreads();
    {
      int xl = tid >> 4, xk = (tid & 15) * 4;
      f32x4 xv = *(const f32x4*)(xd + ((size_t)b * LN + l0 + xl) * KN + xk);
      union { short h[4]; int i[2]; } u;
      u.h[0] = f2b(xv[0]); u.h[1] = f2b(xv[1]); u.h[2] = f2b(xv[2]); u.h[3] = f2b(xv[3]);
      int* dst = (int*)(&xT[xl][xk]);
      dst[0] = u.i[0]; dst[1] = u.i[1];
    }
#pragma unroll
    for (int lp = 0; lp < 4; ++lp) {
      int vl = (tid >> 6) + lp * 8;
      const float* vrow = vals + ((size_t)b * LN + l0 + vl) * EN + eb;
#pragma unroll
      for (int u2 = 0; u2 < 4; ++u2) {
        int e = (tid & 63) + u2 * 64;
        vT[e][vl] = f2b(vrow[e]);
      }
    }
    if (tid < 32) { smm[tid] = mzb[l0 + tid]; smz[tid] = rzb[l0 + tid]; }
    __syncthreads();
#pragma unroll
    for (int t2 = 0; t2 < 2; ++t2) {
      const short* xr = &xT[t2 * 16 + row][0];
      bf16x8 xb0 = *(const bf16x8*)(xr + 8 * g);
      bf16x8 xb1 = *(const bf16x8*)(xr + 32 + 8 * g);
      f32x4 sa = {0.f, 0.f, 0.f, 0.f};
      sa = __builtin_amdgcn_mfma_f32_16x16x32_bf16(ya0, xb0, sa, 0, 0, 0);
      sa = __builtin_amdgcn_mfma_f32_16x16x32_bf16(ya1, xb1, sa, 0, 0, 0);
      int lcol = t2 * 16 + row;
      float mm = smm[lcol], zz = smz[lcol];
#pragma unroll
      for (int r = 0; r < 4; ++r) {
        float p2 = __expf(sa[r] * 0.125f - mm) * zz;
        pT[w * 16 + 4 * g + r][lcol] = f2b(p2);
      }
    }
    __syncthreads();
    bf16x8 pa;
    {
      const int* pi = (const int*)(&pT[w * 16 + row][0] + 8 * g);
      union { int i[4]; bf16x8 f; } u;
      u.i[0] = pi[0]; u.i[1] = pi[1]; u.i[2] = pi[2]; u.i[3] = pi[3];
      pa = u.f;
    }
#pragma unroll
    for (int n = 0; n < 16; ++n) {
      const int* vi = (const int*)(&vT[n * 16 + row][0] + 8 * g);
      union { int i[4]; bf16x8 f; } u;
      u.i[0] = vi[0]; u.i[1] = vi[1]; u.i[2] = vi[2]; u.i[3] = vi[3];
      acc[n] = __builtin_amdgcn_mfma_f32_16x16x32_bf16(pa, u.f, acc[n], 0, 0, 0);
    }
  }
#pragma unroll
  for (int n = 0; n < 16; ++n)
#pragma unroll
    for (int r = 0; r < 4; ++r) {
      int h = hb + w * 16 + 4 * g + r;
      int e = eb + n * 16 + row;
      out[((size_t)b * HN + h) * EN + e] = acc[n][r];
    }
}

extern "C" void kernel_launch(void* const* d_in, const int* in_sizes, int n_in,
                              void* d_out, int out_size, void* d_ws, size_t ws_size,
                              hipStream_t stream) {
  const float* vals = (const float*)d_in[2];
  const float* xd = (const float*)d_in[3];
  const float* yd = (const float*)d_in[4];
  float* out = (float*)d_out;

  if (ws_size >= 40501248ull) {
    char* wsb = (char*)d_ws;
    short* valsT = (short*)wsb;                       // 33554432 B
    short* xbuf  = (short*)(wsb + 33554432);          //  4194304 B
    short* ybuf  = (short*)(wsb + 37748736);          //  2097152 B
    float* ps    = (float*)(wsb + 39845888);          //   524288 B
    float* wv    = (float*)(wsb + 40370176);          //   131072 B

    prep_cvt2<<<dim3(1536), 256, 0, stream>>>(xd, xbuf, yd, ybuf);
    k_pv_stats<<<dim3(5120), 256, 0, stream>>>(vals, valsT, xbuf, ybuf, ps);
    k_comb<<<dim3(BN * LN / 256), 256, 0, stream>>>(ps, wv);
    k_main5<<<dim3(256), 512, 0, stream>>>(valsT, xbuf, ybuf, wv, out);
  } else {
    float* mz = (float*)d_ws;
    k_stats_o<<<dim3(LN / 64, BN), 256, 0, stream>>>(xd, yd, mz);
    k_main_o<<<dim3(HN / 128, EN / 256, BN), 512, 0, stream>>>(vals, xd, yd, mz, out);
  }
}